// Round 1
// baseline (1026.096 us; speedup 1.0000x reference)
//
#include <hip/hip_runtime.h>
#include <hip/hip_bf16.h>

#define NTHREADS 256

// ---------------- degree / normalization ----------------

__global__ void deg_init_k(float* deg, int* counts, int n) {
    int i = blockIdx.x * blockDim.x + threadIdx.x;
    if (i < n) { deg[i] = 1.0f; counts[i] = 0; }   // self-loop weight 1
}

__global__ void deg_accum_k(const int* __restrict__ row, const float* __restrict__ w,
                            float* deg, int e) {
    int i = blockIdx.x * blockDim.x + threadIdx.x;
    if (i < e) atomicAdd(&deg[row[i]], w[i]);
}

__global__ void dinv_k(float* deg, int n) {
    int i = blockIdx.x * blockDim.x + threadIdx.x;
    if (i < n) deg[i] = rsqrtf(fmaxf(deg[i], 1e-12f));   // in-place: deg -> dinv
}

// ---------------- CSR build (by destination col) ----------------

__global__ void count_k(const int* __restrict__ col, int* counts, int e) {
    int i = blockIdx.x * blockDim.x + threadIdx.x;
    if (i < e) atomicAdd(&counts[col[i]], 1);
}

__global__ void scan1_k(const int* __restrict__ counts, int* offsets, int* blockSums, int n) {
    __shared__ int s[256];
    int tid = threadIdx.x;
    int idx = blockIdx.x * 256 + tid;
    int v = (idx < n) ? counts[idx] : 0;
    s[tid] = v;
    __syncthreads();
    for (int off = 1; off < 256; off <<= 1) {
        int t = (tid >= off) ? s[tid - off] : 0;
        __syncthreads();
        s[tid] += t;
        __syncthreads();
    }
    if (idx < n) offsets[idx] = s[tid] - v;        // local exclusive
    if (tid == 255) blockSums[blockIdx.x] = s[255]; // block total
}

__global__ void scan2_k(int* blockSums, int nb) {
    __shared__ int s[1024];
    int tid = threadIdx.x;
    int v = (tid < nb) ? blockSums[tid] : 0;
    s[tid] = v;
    __syncthreads();
    for (int off = 1; off < 1024; off <<= 1) {
        int t = (tid >= off) ? s[tid - off] : 0;
        __syncthreads();
        s[tid] += t;
        __syncthreads();
    }
    if (tid < nb) blockSums[tid] = s[tid] - v;      // exclusive
}

__global__ void scan3_k(int* offsets, const int* __restrict__ blockSums, int* cursor,
                        int n, int total) {
    int idx = blockIdx.x * blockDim.x + threadIdx.x;
    if (idx < n) {
        offsets[idx] += blockSums[idx >> 8];
        cursor[idx] = 0;
    }
    if (idx == n) offsets[n] = total;
}

__global__ void scatter_k(const int* __restrict__ row, const int* __restrict__ col,
                          const float* __restrict__ w, const float* __restrict__ dinv,
                          const int* __restrict__ offsets, int* cursor,
                          int* csr_src, float* csr_w, int e) {
    int i = blockIdx.x * blockDim.x + threadIdx.x;
    if (i >= e) return;
    int r = row[i], c = col[i];
    int pos = offsets[c] + atomicAdd(&cursor[c], 1);
    csr_src[pos] = r;
    csr_w[pos] = dinv[r] * w[i] * dinv[c];
}

// ---------------- propagation: one wave (64 lanes) per node ----------------

template <bool FIRST>
__global__ void prop_k(const float* __restrict__ h_in, float* __restrict__ h_out,
                       float* __restrict__ acc, const float* __restrict__ dinv,
                       const int* __restrict__ offsets, const int* __restrict__ csr_src,
                       const float* __restrict__ csr_w, int n) {
    int c = blockIdx.x;
    if (c >= n) return;
    int t = threadIdx.x;  // 64 lanes = 64 features
    float di = dinv[c];
    float sum = di * di * h_in[(size_t)c * 64 + t];  // self-loop, weight dinv[c]^2
    int beg = offsets[c], end = offsets[c + 1];
    for (int j = beg; j < end; ++j) {
        int s = csr_src[j];
        float wv = csr_w[j];
        sum += wv * h_in[(size_t)s * 64 + t];
    }
    size_t o = (size_t)c * 64 + t;
    h_out[o] = sum;
    if (FIRST) acc[o] = sum;
    else       acc[o] += sum;
}

// ---------------- fused epilogue: scale + MLP(64->64 relu ->32) ----------------

__global__ __launch_bounds__(256) void mlp_k(const float* __restrict__ acc,
                                             const float* __restrict__ x,
                                             const float* __restrict__ W0,
                                             const float* __restrict__ b0,
                                             const float* __restrict__ W1,
                                             const float* __restrict__ b1,
                                             float* __restrict__ out, int n) {
    __shared__ float W0s[64 * 64];
    __shared__ float W1s[64 * 32];
    __shared__ float b0s[64];
    __shared__ float b1s[32];
    __shared__ float z[32][64];
    __shared__ float hid[32][64];
    int tid = threadIdx.x;
    for (int i = tid; i < 64 * 64; i += 256) W0s[i] = W0[i];
    for (int i = tid; i < 64 * 32; i += 256) W1s[i] = W1[i];
    if (tid < 64) b0s[tid] = b0[tid];
    else if (tid < 96) b1s[tid - 64] = b1[tid - 64];

    int base = blockIdx.x * 32;
    // stage z = acc*0.09 + 0.1*x  (32 nodes x 64 feats)
    for (int r = 0; r < 8; ++r) {
        int idx = r * 256 + tid;
        int nn = idx >> 6, f = idx & 63;
        int node = base + nn;
        float v = 0.f;
        if (node < n) v = acc[(size_t)node * 64 + f] * 0.09f + 0.1f * x[(size_t)node * 64 + f];
        z[nn][f] = v;
    }
    __syncthreads();
    // hidden = relu(z @ W0 + b0)
    for (int r = 0; r < 8; ++r) {
        int idx = r * 256 + tid;
        int nn = idx >> 6, j = idx & 63;
        float s = b0s[j];
#pragma unroll
        for (int i = 0; i < 64; ++i) s += z[nn][i] * W0s[i * 64 + j];
        hid[nn][j] = fmaxf(s, 0.f);
    }
    __syncthreads();
    // out = hid @ W1 + b1
    for (int r = 0; r < 4; ++r) {
        int idx = r * 256 + tid;
        int nn = idx >> 5, o = idx & 31;
        int node = base + nn;
        if (node >= n) continue;
        float s = b1s[o];
#pragma unroll
        for (int i = 0; i < 64; ++i) s += hid[nn][i] * W1s[i * 32 + o];
        out[(size_t)node * 32 + o] = s;
    }
}

// ---------------- launch ----------------

extern "C" void kernel_launch(void* const* d_in, const int* in_sizes, int n_in,
                              void* d_out, int out_size, void* d_ws, size_t ws_size,
                              hipStream_t stream) {
    const float* x   = (const float*)d_in[0];
    const int*   ei  = (const int*)d_in[1];
    const float* ew  = (const float*)d_in[2];
    const float* W0  = (const float*)d_in[3];
    const float* b0  = (const float*)d_in[4];
    const float* W1  = (const float*)d_in[5];
    const float* b1  = (const float*)d_in[6];
    float* out = (float*)d_out;

    const int N = in_sizes[0] / 64;   // 100000
    const int E = in_sizes[2];        // 1200000
    const int* row = ei;
    const int* col = ei + E;

    // workspace carve-up (all 256B aligned)
    char* p = (char*)d_ws;
    auto alloc = [&](size_t bytes) -> void* {
        void* r = (void*)p;
        p += (bytes + 255) & ~(size_t)255;
        return r;
    };
    float* dinv      = (float*)alloc((size_t)N * 4);
    int*   counts    = (int*)alloc((size_t)N * 4);       // also reused as scatter cursor
    int*   offsets   = (int*)alloc((size_t)(N + 1) * 4);
    int    nb        = (N + 255) / 256;
    int*   blockSums = (int*)alloc((size_t)nb * 4);
    int*   csr_src   = (int*)alloc((size_t)E * 4);
    float* csr_w     = (float*)alloc((size_t)E * 4);
    float* h0        = (float*)alloc((size_t)N * 64 * 4);
    float* h1        = (float*)alloc((size_t)N * 64 * 4);
    float* acc       = (float*)alloc((size_t)N * 64 * 4);

    int gN = (N + NTHREADS - 1) / NTHREADS;
    int gE = (E + NTHREADS - 1) / NTHREADS;

    deg_init_k<<<gN, NTHREADS, 0, stream>>>(dinv, counts, N);
    deg_accum_k<<<gE, NTHREADS, 0, stream>>>(row, ew, dinv, E);
    dinv_k<<<gN, NTHREADS, 0, stream>>>(dinv, N);

    count_k<<<gE, NTHREADS, 0, stream>>>(col, counts, E);
    scan1_k<<<nb, 256, 0, stream>>>(counts, offsets, blockSums, N);
    scan2_k<<<1, 1024, 0, stream>>>(blockSums, nb);
    scan3_k<<<(N + 1 + NTHREADS - 1) / NTHREADS, NTHREADS, 0, stream>>>(offsets, blockSums,
                                                                        counts, N, E);
    scatter_k<<<gE, NTHREADS, 0, stream>>>(row, col, ew, dinv, offsets, counts,
                                           csr_src, csr_w, E);

    // K = 10 propagation steps, ping-pong h buffers
    prop_k<true><<<N, 64, 0, stream>>>(x, h0, acc, dinv, offsets, csr_src, csr_w, N);
    const float* hin = h0;
    float* hout = h1;
    for (int k = 1; k < 10; ++k) {
        prop_k<false><<<N, 64, 0, stream>>>(hin, hout, acc, dinv, offsets, csr_src, csr_w, N);
        const float* tmp = hout;
        hout = (float*)hin;
        hin = tmp;
    }

    mlp_k<<<(N + 31) / 32, 256, 0, stream>>>(acc, x, W0, b0, W1, b1, out, N);
}